// Round 3
// baseline (36.558 us; speedup 1.0000x reference)
//
#include <hip/hip_runtime.h>
#include <math.h>

namespace {

constexpr int Bn = 8;
constexpr int Hn = 256;
constexpr int Wn = 256;
constexpr int HW = Hn * Wn;       // 65536
constexpr int Ntot = Bn * HW;     // 524288
constexpr float INF_F = 131138.0f; // sum(n*n for n in shape)+1
constexpr float EPSv = 1e-6f;

// 256-thread block sum; returns full sum to all threads. Fixed order -> deterministic.
__device__ __forceinline__ float blkred(float v, float* sm) {
    #pragma unroll
    for (int o = 32; o > 0; o >>= 1) v += __shfl_down(v, o, 64);
    int lane = threadIdx.x & 63, wid = threadIdx.x >> 6;
    __syncthreads();
    if (lane == 0) sm[wid] = v;
    __syncthreads();
    return sm[0] + sm[1] + sm[2] + sm[3];
}

// Wave-cooperative exact 1D DT over one 256-line staged in LDS as
// u[j] = f[j] + j^2:  res(i) = i^2 + min_j (u[j] - 2*j*i).
// All values exact integers < 2^24 -> bit-identical to brute force.
// Lane l computes i in {l, l+64, l+128, l+192}: 4 outputs per float4 read
// (4x fewer LDS reads than thread-per-i). min3 fusion via nested fminf.
__device__ __forceinline__ void dt_wave(const float* __restrict__ u,
                                        int lane, float res[4]) {
    const float4* u4 = reinterpret_cast<const float4*>(u);
    float fi[4], mA[4], mB[4];
    #pragma unroll
    for (int r = 0; r < 4; ++r) {
        fi[r] = (float)(lane + 64 * r);
        mA[r] = 3.0e38f; mB[r] = 3.0e38f;
    }
    #pragma unroll 8
    for (int q = 0; q < 64; ++q) {
        float4 uu = u4[q];             // wave-uniform broadcast read
        float j0 = (float)(-2 * (4 * q + 0));
        float j1 = (float)(-2 * (4 * q + 1));
        float j2 = (float)(-2 * (4 * q + 2));
        float j3 = (float)(-2 * (4 * q + 3));
        #pragma unroll
        for (int r = 0; r < 4; ++r) {
            float c0 = fmaf(j0, fi[r], uu.x);
            float c1 = fmaf(j1, fi[r], uu.y);
            float c2 = fmaf(j2, fi[r], uu.z);
            float c3 = fmaf(j3, fi[r], uu.w);
            mA[r] = fminf(fminf(mA[r], c0), c1);   // -> v_min3_f32
            mB[r] = fminf(fminf(mB[r], c2), c3);
        }
    }
    #pragma unroll
    for (int r = 0; r < 4; ++r)
        res[r] = fminf(mA[r], mB[r]) + fi[r] * fi[r];
}

// Fused kernel A+W: block = row h. Per thread (pixel w): sigmoid/dice/focal
// partials over 8 batches, axis-B DT (n=8) in regs, then the 8 W-lines of this
// row are staged in LDS and W-DT'd wave-cooperatively (wave -> 2 lines).
__global__ __launch_bounds__(256) void kAW(const float* __restrict__ lg,
                                           const float* __restrict__ tg,
                                           float* __restrict__ g,
                                           float* __restrict__ pa) {
    int h = blockIdx.x, w = threadIdx.x;
    int t = h * Wn + w;
    float sp = 0.f, st = 0.f, spt = 0.f, fo = 0.f;
    float fv[Bn];
    #pragma unroll
    for (int b = 0; b < Bn; b++) {
        float x  = lg[b * HW + t];
        float tv = tg[b * HW + t];
        float p  = 1.f / (1.f + expf(-x));
        sp  += p;
        st  += tv;
        spt += p * tv;
        float ce = fmaxf(x, 0.f) - x * tv + log1pf(expf(-fabsf(x)));
        float pt = p * tv + (1.f - p) * (1.f - tv);
        float om = 1.f - pt;
        fo += 0.25f * om * om * ce;          // ALPHA=0.25, GAMMA=2
        fv[b] = (tv > 0.5f) ? INF_F : 0.f;
    }
    // axis-B DT (exact) + stage u = f1 + w^2 into LDS
    __shared__ __align__(16) float u[Bn][Wn];
    float fw = (float)w;
    #pragma unroll
    for (int i = 0; i < Bn; i++) {
        float m = fv[0] + (float)(i * i);
        #pragma unroll
        for (int j = 1; j < Bn; j++) {
            int d = i - j;
            m = fminf(m, fv[j] + (float)(d * d));
        }
        u[i][w] = m + fw * fw;
    }
    __syncthreads();
    int wv = threadIdx.x >> 6, lane = threadIdx.x & 63;
    #pragma unroll
    for (int s = 0; s < 2; ++s) {
        int b = 2 * wv + s;
        float res[4];
        dt_wave(u[b], lane, res);
        #pragma unroll
        for (int r = 0; r < 4; ++r)
            g[(size_t)b * HW + h * Wn + lane + 64 * r] = res[r];
    }
    __shared__ float sm[4];
    sp  = blkred(sp, sm);
    st  = blkred(st, sm);
    spt = blkred(spt, sm);
    fo  = blkred(fo, sm);
    if (threadIdx.x == 0) {
        float* o = pa + blockIdx.x * 4;
        o[0] = sp; o[1] = st; o[2] = spt; o[3] = fo;
    }
}

// Kernel H: wave per (b,w) column line. Strided gather of g (L2/L3-resident,
// just written) into LDS, H-DT, fused sqrt + boundary term + block reduce.
__global__ __launch_bounds__(256) void kH(const float* __restrict__ g,
                                          const float* __restrict__ lg,
                                          float* __restrict__ bp) {
    __shared__ __align__(16) float u[4][Hn];
    __shared__ float sm[4];
    int wv = threadIdx.x >> 6, lane = threadIdx.x & 63;
    int line = blockIdx.x * 4 + wv;        // (b, w)
    int b = line >> 8, w = line & 255;
    const float* gb = g  + (size_t)b * HW + w;
    const float* lb = lg + (size_t)b * HW + w;
    float xv[4];
    #pragma unroll
    for (int r = 0; r < 4; ++r) {
        int i = lane + 64 * r;
        u[wv][i] = gb[(size_t)i * Wn] + (float)(i * i);
        xv[r] = lb[(size_t)i * Wn];
    }
    __syncthreads();
    float res[4];
    dt_wave(u[wv], lane, res);
    float acc = 0.f;
    #pragma unroll
    for (int r = 0; r < 4; ++r) {
        float dm = sqrtf(res[r]);
        float s = 1.f / (1.f + expf(xv[r]));   // = 1 - sigmoid(x)
        acc += dm * s * s;
    }
    acc = blkred(acc, sm);
    if (threadIdx.x == 0) bp[blockIdx.x] = acc;
}

// Kernel D: final combine. 256 threads, one block.
__global__ __launch_bounds__(256) void kD(const float* __restrict__ pa,
                                          const float* __restrict__ bp,
                                          float* __restrict__ out) {
    __shared__ float sm[4];
    int t = threadIdx.x;
    float sp  = pa[t * 4 + 0];
    float st  = pa[t * 4 + 1];
    float spt = pa[t * 4 + 2];
    float fo  = pa[t * 4 + 3];
    float bs  = bp[t] + bp[t + 256];
    sp  = blkred(sp, sm);
    st  = blkred(st, sm);
    spt = blkred(spt, sm);
    fo  = blkred(fo, sm);
    bs  = blkred(bs, sm);
    if (t == 0) {
        float dice = 1.f - (2.f * spt + EPSv) / (sp + st + EPSv);
        float boundary = bs / (float)Ntot;
        float focal = fo / (float)Ntot;
        out[0] = 1.0f * dice + 0.5f * boundary + 1.0f * focal;
    }
}

} // namespace

extern "C" void kernel_launch(void* const* d_in, const int* in_sizes, int n_in,
                              void* d_out, int out_size, void* d_ws, size_t ws_size,
                              hipStream_t stream) {
    const float* lg = (const float*)d_in[0];   // logits  [8,1,256,256] f32
    const float* tg = (const float*)d_in[1];   // targets [8,1,256,256] f32
    float* ws = (float*)d_ws;
    float* g  = ws;                      // Ntot floats ([b][h][w], post B+W DT)
    float* pa = ws + Ntot;               // 256 blocks * 4 partials
    float* bp = ws + Ntot + 1024;        // 512 boundary partials

    kAW<<<Hn, 256, 0, stream>>>(lg, tg, g, pa);
    kH<<<Bn * Wn / 4, 256, 0, stream>>>(g, lg, bp);
    kD<<<1, 256, 0, stream>>>(pa, bp, (float*)d_out);
}

// Round 4
// 33.433 us; speedup vs baseline: 1.0935x; 1.0935x over previous
//
#include <hip/hip_runtime.h>
#include <math.h>

namespace {

constexpr int Bn = 8;
constexpr int Hn = 256;
constexpr int Wn = 256;
constexpr int HW = Hn * Wn;       // 65536
constexpr int Ntot = Bn * HW;     // 524288
constexpr float INF_F = 131138.0f; // sum(n*n for n in shape)+1
constexpr float EPSv = 1e-6f;

// 256-thread block sum; returns full sum to all threads. Fixed order -> deterministic.
__device__ __forceinline__ float blkred(float v, float* sm) {
    #pragma unroll
    for (int o = 32; o > 0; o >>= 1) v += __shfl_down(v, o, 64);
    int lane = threadIdx.x & 63, wid = threadIdx.x >> 6;
    __syncthreads();
    if (lane == 0) sm[wid] = v;
    __syncthreads();
    return sm[0] + sm[1] + sm[2] + sm[3];
}

// Wave-cooperative exact 1D DT over a 256-line staged in LDS as
// u[j] = f[j] + j^2:  res(i) = i^2 + min_j (u[j] - 2*j*i).
// All intermediates exact integers < 2^24 -> bit-identical to brute force.
// Lane l computes i in {4l, 4l+1, 4l+2, 4l+3} -> float4 store.
// 8 independent min chains/lane; nested fminf fuses to v_min3_f32.
__device__ __forceinline__ void dt_wave4(const float* __restrict__ u,
                                         int lane, float res[4]) {
    const float4* u4 = reinterpret_cast<const float4*>(u);
    float fi[4], mA[4], mB[4];
    #pragma unroll
    for (int r = 0; r < 4; ++r) {
        fi[r] = (float)(4 * lane + r);
        mA[r] = 3.0e38f; mB[r] = 3.0e38f;
    }
    #pragma unroll 8
    for (int q = 0; q < 64; ++q) {
        float4 uu = u4[q];             // wave-uniform broadcast read
        float j0 = (float)(-2 * (4 * q + 0));
        float j1 = (float)(-2 * (4 * q + 1));
        float j2 = (float)(-2 * (4 * q + 2));
        float j3 = (float)(-2 * (4 * q + 3));
        #pragma unroll
        for (int r = 0; r < 4; ++r) {
            mA[r] = fminf(fminf(mA[r], fmaf(j0, fi[r], uu.x)),
                          fmaf(j1, fi[r], uu.y));
            mB[r] = fminf(fminf(mB[r], fmaf(j2, fi[r], uu.z)),
                          fmaf(j3, fi[r], uu.w));
        }
    }
    #pragma unroll
    for (int r = 0; r < 4; ++r)
        res[r] = fminf(mA[r], mB[r]) + fi[r] * fi[r];
}

// Kernel A: per-(h,w) pixel, loop batches. Sigmoid + dice/focal partials,
// (1-p)^2 buffer for the boundary term, axis-B DT (n=8) in regs.
__global__ __launch_bounds__(256) void kA(const float* __restrict__ lg,
                                          const float* __restrict__ tg,
                                          float* __restrict__ f1,
                                          float* __restrict__ sq,
                                          float* __restrict__ pa) {
    int t = blockIdx.x * 256 + threadIdx.x;   // 0..HW-1
    float sp = 0.f, st = 0.f, spt = 0.f, fo = 0.f;
    float fv[Bn];
    #pragma unroll
    for (int b = 0; b < Bn; b++) {
        float x  = lg[b * HW + t];
        float tv = tg[b * HW + t];
        float p  = 1.f / (1.f + expf(-x));
        sp  += p;
        st  += tv;
        spt += p * tv;
        float ce = fmaxf(x, 0.f) - x * tv + log1pf(expf(-fabsf(x)));
        float pt = p * tv + (1.f - p) * (1.f - tv);
        float om = 1.f - pt;
        fo += 0.25f * om * om * ce;          // ALPHA=0.25, GAMMA=2
        float qn = 1.f - p;
        sq[b * HW + t] = qn * qn;
        fv[b] = (tv > 0.5f) ? INF_F : 0.f;
    }
    // exact 1D squared-distance transform along batch axis (n=8)
    #pragma unroll
    for (int i = 0; i < Bn; i++) {
        float m = fv[0] + (float)(i * i);
        #pragma unroll
        for (int j = 1; j < Bn; j++) {
            int d = i - j;
            m = fminf(m, fv[j] + (float)(d * d));
        }
        f1[i * HW + t] = m;
    }
    __shared__ float sm[4];
    sp  = blkred(sp, sm);
    st  = blkred(st, sm);
    spt = blkred(spt, sm);
    fo  = blkred(fo, sm);
    if (threadIdx.x == 0) {
        float* o = pa + blockIdx.x * 4;
        o[0] = sp; o[1] = st; o[2] = spt; o[3] = fo;
    }
}

// Kernel W: DT along W. 4 lines/block, one per wave; float4 coalesced I/O.
__global__ __launch_bounds__(256) void kW(const float* __restrict__ f1,
                                          float* __restrict__ g) {
    __shared__ __align__(16) float u[4][Wn];
    int wv = threadIdx.x >> 6, lane = threadIdx.x & 63;
    int line = blockIdx.x * 4 + wv;        // b*Hn + h
    float4 v = reinterpret_cast<const float4*>(f1 + (size_t)line * Wn)[lane];
    float j0 = (float)(4 * lane);
    v.x += j0 * j0;
    v.y += (j0 + 1.f) * (j0 + 1.f);
    v.z += (j0 + 2.f) * (j0 + 2.f);
    v.w += (j0 + 3.f) * (j0 + 3.f);
    reinterpret_cast<float4*>(u[wv])[lane] = v;
    __syncthreads();
    float res[4];
    dt_wave4(u[wv], lane, res);
    float4 o = make_float4(res[0], res[1], res[2], res[3]);
    reinterpret_cast<float4*>(g + (size_t)line * Wn)[lane] = o;
}

// Kernel T: per-batch 32x32 tile transpose of BOTH g and sq.
__global__ __launch_bounds__(256) void kT(const float* __restrict__ g,
                                          const float* __restrict__ sq,
                                          float* __restrict__ gT,
                                          float* __restrict__ sqT) {
    int bid = blockIdx.x;          // b*64 + ty*8 + tx
    int b  = bid >> 6;
    int ty = (bid >> 3) & 7;
    int tx = bid & 7;
    __shared__ float t0[32][33];
    __shared__ float t1[32][33];
    int c  = threadIdx.x & 31;
    int r0 = threadIdx.x >> 5;     // 0..7
    const float* gb = g  + (size_t)b * HW;
    const float* sb = sq + (size_t)b * HW;
    #pragma unroll
    for (int k = 0; k < 4; ++k) {
        int r = r0 + 8 * k;
        t0[r][c] = gb[(ty * 32 + r) * Wn + tx * 32 + c];
        t1[r][c] = sb[(ty * 32 + r) * Wn + tx * 32 + c];
    }
    __syncthreads();
    float* gTb = gT  + (size_t)b * HW;
    float* sTb = sqT + (size_t)b * HW;
    #pragma unroll
    for (int k = 0; k < 4; ++k) {
        int r = r0 + 8 * k;        // w within tile
        gTb[(tx * 32 + r) * Hn + ty * 32 + c] = t0[c][r];
        sTb[(tx * 32 + r) * Hn + ty * 32 + c] = t1[c][r];
    }
}

// Kernel H: DT along H on transposed layout — fully contiguous. Fused
// sqrt + boundary term (from sqT) + block reduce.
__global__ __launch_bounds__(256) void kH(const float* __restrict__ gT,
                                          const float* __restrict__ sqT,
                                          float* __restrict__ bp) {
    __shared__ __align__(16) float u[4][Hn];
    __shared__ float sm[4];
    int wv = threadIdx.x >> 6, lane = threadIdx.x & 63;
    int line = blockIdx.x * 4 + wv;        // b*Wn + w
    float4 v = reinterpret_cast<const float4*>(gT + (size_t)line * Hn)[lane];
    float j0 = (float)(4 * lane);
    v.x += j0 * j0;
    v.y += (j0 + 1.f) * (j0 + 1.f);
    v.z += (j0 + 2.f) * (j0 + 2.f);
    v.w += (j0 + 3.f) * (j0 + 3.f);
    reinterpret_cast<float4*>(u[wv])[lane] = v;
    float4 sv = reinterpret_cast<const float4*>(sqT + (size_t)line * Hn)[lane];
    __syncthreads();
    float res[4];
    dt_wave4(u[wv], lane, res);
    float acc = sqrtf(res[0]) * sv.x + sqrtf(res[1]) * sv.y
              + sqrtf(res[2]) * sv.z + sqrtf(res[3]) * sv.w;
    acc = blkred(acc, sm);
    if (threadIdx.x == 0) bp[blockIdx.x] = acc;
}

// Kernel D: final combine. 256 threads, one block.
__global__ __launch_bounds__(256) void kD(const float* __restrict__ pa,
                                          const float* __restrict__ bp,
                                          float* __restrict__ out) {
    __shared__ float sm[4];
    int t = threadIdx.x;
    float sp  = pa[t * 4 + 0];
    float st  = pa[t * 4 + 1];
    float spt = pa[t * 4 + 2];
    float fo  = pa[t * 4 + 3];
    float bs  = bp[t] + bp[t + 256];
    sp  = blkred(sp, sm);
    st  = blkred(st, sm);
    spt = blkred(spt, sm);
    fo  = blkred(fo, sm);
    bs  = blkred(bs, sm);
    if (t == 0) {
        float dice = 1.f - (2.f * spt + EPSv) / (sp + st + EPSv);
        float boundary = bs / (float)Ntot;
        float focal = fo / (float)Ntot;
        out[0] = 1.0f * dice + 0.5f * boundary + 1.0f * focal;
    }
}

} // namespace

extern "C" void kernel_launch(void* const* d_in, const int* in_sizes, int n_in,
                              void* d_out, int out_size, void* d_ws, size_t ws_size,
                              hipStream_t stream) {
    const float* lg = (const float*)d_in[0];   // logits  [8,1,256,256] f32
    const float* tg = (const float*)d_in[1];   // targets [8,1,256,256] f32
    float* ws  = (float*)d_ws;
    float* f1  = ws;                       // [b][h][w] post B-DT
    float* g   = ws + Ntot;                // [b][h][w] post W-DT
    float* sq  = ws + 2 * Ntot;            // (1-p)^2, [b][h][w]
    float* gT  = ws + 3 * Ntot;            // [b][w][h]
    float* sqT = ws + 4 * Ntot;            // [b][w][h]
    float* pa  = ws + 5 * Ntot;            // 256 blocks * 4 partials
    float* bp  = ws + 5 * Ntot + 1024;     // 512 boundary partials

    kA<<<HW / 256, 256, 0, stream>>>(lg, tg, f1, sq, pa);
    kW<<<Bn * Hn / 4, 256, 0, stream>>>(f1, g);
    kT<<<Bn * 64, 256, 0, stream>>>(g, sq, gT, sqT);
    kH<<<Bn * Wn / 4, 256, 0, stream>>>(gT, sqT, bp);
    kD<<<1, 256, 0, stream>>>(pa, bp, (float*)d_out);
}